// Round 1
// 368.766 us; speedup vs baseline: 1.0486x; 1.0486x over previous
//
#include <hip/hip_runtime.h>
#include <hip/hip_bf16.h>
#include <math.h>

#define N 320
#define NN (N * N)          // 102400
#define SST 324             // LDS fp32 row stride for S scratch

typedef float f32x16 __attribute__((ext_vector_type(16)));
typedef short s16x8  __attribute__((ext_vector_type(8)));

#define MFMA32(a, b, c) __builtin_amdgcn_mfma_f32_32x32x16_bf16((a), (b), (c), 0, 0, 0)

union U4V { uint4 q; s16x8 v; };
union UAV { unsigned u[4]; s16x8 v; };

// truncation split: x = hi + lo with hi,lo bf16 (round-toward-zero; rel err ~2^-16 combined)
__device__ inline void split2(float x0, float x1, unsigned& hi, unsigned& lo) {
    unsigned u0 = __float_as_uint(x0), u1 = __float_as_uint(x1);
    hi = (u0 >> 16) | (u1 & 0xFFFF0000u);
    float d0 = x0 - __uint_as_float(u0 & 0xFFFF0000u);
    float d1 = x1 - __uint_as_float(u1 & 0xFFFF0000u);
    lo = (__float_as_uint(d0) >> 16) | (__float_as_uint(d1) & 0xFFFF0000u);
}

// ---------------- fused prep: zero wbuf + out, colsum partials, pack s^T, pack W^T ----
// block roles:
//   [  0,100) zero wbuf        (100*256 float4 = 102400 floats)
//   [100,200) zero out         (same count)
//   [200,210) colsum partials  cpart[chunk*320+e] = sum_{t in chunk} s[t][e]  (8 chunks)
//   [210,260) pack s^T  (4 sub-blocks of 64 lanes per 256-thread block)
//   [260,310) pack W^T
__global__ __launch_bounds__(256) void prep_kernel(
    const float* __restrict__ s, const float* __restrict__ W,
    float* __restrict__ wbuf, float* __restrict__ out, float* __restrict__ cpart,
    uint4* __restrict__ spH, uint4* __restrict__ spL,
    uint4* __restrict__ wpH, uint4* __restrict__ wpL)
{
    const int bid = blockIdx.x;
    const int tid = threadIdx.x;
    if (bid < 100) {
        ((float4*)wbuf)[bid * 256 + tid] = make_float4(0.f, 0.f, 0.f, 0.f);
    } else if (bid < 200) {
        ((float4*)out)[(bid - 100) * 256 + tid] = make_float4(0.f, 0.f, 0.f, 0.f);
    } else if (bid < 210) {
        int idx = (bid - 200) * 256 + tid;          // 0..2559
        int e = idx % N;
        int chunk = idx / N;
        const float* sp = s + (size_t)chunk * 40 * N + e;
        float a[8];
#pragma unroll
        for (int u = 0; u < 8; ++u) a[u] = 0.f;
        for (int t = 0; t < 40; t += 8) {
#pragma unroll
            for (int u = 0; u < 8; ++u) a[u] += sp[(size_t)(t + u) * N];
        }
        cpart[idx] = ((a[0] + a[1]) + (a[2] + a[3])) + ((a[4] + a[5]) + (a[6] + a[7]));
    } else if (bid < 260) {
        int sub = (bid - 210) * 4 + (tid >> 6);     // 0..199 = et*20 + ts
        int l = tid & 63;
        int et = sub / 20, ts = sub % 20;
        int e = et * 32 + (l & 31);
        int t0 = ts * 16 + (l >> 5) * 8;
        unsigned hi[4], lo[4];
#pragma unroll
        for (int d = 0; d < 4; ++d)
            split2(s[(size_t)(t0 + 2 * d) * N + e], s[(size_t)(t0 + 2 * d + 1) * N + e],
                   hi[d], lo[d]);
        spH[sub * 64 + l] = make_uint4(hi[0], hi[1], hi[2], hi[3]);
        spL[sub * 64 + l] = make_uint4(lo[0], lo[1], lo[2], lo[3]);
    } else {
        int sub = (bid - 260) * 4 + (tid >> 6);     // 0..199 = jt*20 + ks
        int l = tid & 63;
        int jt = sub / 20, ks = sub % 20;
        int j = jt * 32 + (l & 31);
        int k0 = ks * 16 + (l >> 5) * 8;
        const float* wr = W + (size_t)j * N + k0;
        unsigned hi[4], lo[4];
#pragma unroll
        for (int d = 0; d < 4; ++d) split2(wr[2 * d], wr[2 * d + 1], hi[d], lo[d]);
        wpH[sub * 64 + l] = make_uint4(hi[0], hi[1], hi[2], hi[3]);
        wpL[sub * 64 + l] = make_uint4(lo[0], lo[1], lo[2], lo[3]);
    }
}

// ---------------- fused MFMA kernel: per (e-slab 32, i) ----------------
// Grid is 1-D (3200) with an XCD swizzle: all 10 e-slabs of one i map to the
// same XCD (bid%8 == i%8) so F_i is served from that XCD's L2 after first touch.
// Both GEMM phases are software-pipelined one iteration ahead (loads for ts+1 /
// ks+1 issued before the split+MFMA of the current iteration).
__global__ __launch_bounds__(640, 5) void fused_kernel(
    const float* __restrict__ fut,
    const uint4* __restrict__ spH, const uint4* __restrict__ spL,
    const uint4* __restrict__ wpH, const uint4* __restrict__ wpL,
    const float* __restrict__ bvec, const float* __restrict__ cpart,
    float* __restrict__ w)
{
    const int bid = blockIdx.x;
    const int i   = (bid / 80) * 8 + (bid & 7);
    const int et  = (bid >> 3) % 10;
    const int tid = threadIdx.x;
    const int wid = tid >> 6;         // wave 0..9 = 32-wide column tile
    const int lane = tid & 63;
    const int l31 = lane & 31;
    const int hf  = lane >> 5;

    // G in LDS: frag-linear, XOR-swizzled 16B chunks.
    // chunk c = ks*2+hf (0..39); addr = (c*32 + (e ^ (c&7)))*8 shorts + j
    __shared__ union {
        unsigned short G[2][40 * 32 * 8];   // [hi/lo] 20KB each
        float S[32 * SST];                  // softmax scratch
    } sm;
    __shared__ float csh[32];
    __shared__ float Mfin[32];
    __shared__ float Ifin[32];

    if (tid < 32) {
        float c = 0.f;
#pragma unroll
        for (int q = 0; q < 8; ++q) c += cpart[q * N + et * 32 + tid];
        csh[tid] = c;
    }

    // ---------------- phase A: G = s^T @ F_i (column tile wid) ----------------
    f32x16 acc;
#pragma unroll
    for (int r = 0; r < 16; ++r) acc[r] = 0.f;

    const float* fbase = fut + (size_t)i * NN + (size_t)(hf * 8) * N + wid * 32 + l31;
    const uint4* aHp = spH + (size_t)(et * 20) * 64 + lane;
    const uint4* aLp = spL + (size_t)(et * 20) * 64 + lane;

    // preload ts = 0
    float f[8];
    U4V ah, al;
    {
#pragma unroll
        for (int j = 0; j < 8; ++j) f[j] = fbase[(size_t)j * N];
        ah.q = aHp[0];
        al.q = aLp[0];
    }
    for (int ts = 0; ts < 19; ++ts) {
        // prefetch ts+1
        float fn[8];
        const float* fp = fbase + (size_t)((ts + 1) * 16) * N;
#pragma unroll
        for (int j = 0; j < 8; ++j) fn[j] = fp[(size_t)j * N];
        U4V ahn, aln;
        ahn.q = aHp[(ts + 1) * 64];
        aln.q = aLp[(ts + 1) * 64];

        // compute ts
        UAV bh, bl;
#pragma unroll
        for (int d = 0; d < 4; ++d) split2(f[2 * d], f[2 * d + 1], bh.u[d], bl.u[d]);
        acc = MFMA32(ah.v, bh.v, acc);
        acc = MFMA32(al.v, bh.v, acc);
        acc = MFMA32(ah.v, bl.v, acc);

#pragma unroll
        for (int j = 0; j < 8; ++j) f[j] = fn[j];
        ah = ahn; al = aln;
    }
    {   // epilogue ts = 19
        UAV bh, bl;
#pragma unroll
        for (int d = 0; d < 4; ++d) split2(f[2 * d], f[2 * d + 1], bh.u[d], bl.u[d]);
        acc = MFMA32(ah.v, bh.v, acc);
        acc = MFMA32(al.v, bh.v, acc);
        acc = MFMA32(ah.v, bl.v, acc);
    }

    // preload phase-B W fragments (ks=0) before the barrier — latency hides under B1
    const uint4* bHp = wpH + (size_t)(wid * 20) * 64 + lane;
    const uint4* bLp = wpL + (size_t)(wid * 20) * 64 + lane;
    U4V wh, wl;
    wh.q = bHp[0];
    wl.q = bLp[0];

    // G -> LDS bf16 hi/lo in frag-linear swizzled layout
    {
        const int c  = wid * 4 + (l31 >> 3);
        const int jj = l31 & 7;
        const int sw = c & 7;
        unsigned short* GH = sm.G[0];
        unsigned short* GL = sm.G[1];
#pragma unroll
        for (int r = 0; r < 16; ++r) {
            int e = (r & 3) + ((r >> 2) << 3) + (hf << 2);
            float x = acc[r];
            unsigned u = __float_as_uint(x);
            float d = x - __uint_as_float(u & 0xFFFF0000u);
            int off = (c * 32 + (e ^ sw)) * 8 + jj;
            GH[off] = (unsigned short)(u >> 16);
            GL[off] = (unsigned short)(__float_as_uint(d) >> 16);
        }
    }
    __syncthreads();   // B1: G + csh visible

    // ---------------- phase B: S = G @ W^T (+ bias) ----------------
    f32x16 acc2;
#pragma unroll
    for (int r = 0; r < 16; ++r) acc2[r] = 0.f;

    const unsigned short* GH = sm.G[0];
    const unsigned short* GL = sm.G[1];

    // preload ks = 0 G fragments
    s16x8 gah, gal;
    {
        int c0 = hf;
        int aoff = (c0 * 32 + (l31 ^ (c0 & 7))) * 8;
        gah = *(const s16x8*)&GH[aoff];
        gal = *(const s16x8*)&GL[aoff];
    }
    for (int ks = 0; ks < 19; ++ks) {
        // prefetch ks+1
        U4V whn, wln;
        whn.q = bHp[(ks + 1) * 64];
        wln.q = bLp[(ks + 1) * 64];
        int c1 = (ks + 1) * 2 + hf;
        int aoff1 = (c1 * 32 + (l31 ^ (c1 & 7))) * 8;
        s16x8 gahn = *(const s16x8*)&GH[aoff1];
        s16x8 galn = *(const s16x8*)&GL[aoff1];

        // compute ks
        acc2 = MFMA32(gah, wh.v, acc2);
        acc2 = MFMA32(gal, wh.v, acc2);
        acc2 = MFMA32(gah, wl.v, acc2);

        gah = gahn; gal = galn;
        wh = whn; wl = wln;
    }
    {   // epilogue ks = 19
        acc2 = MFMA32(gah, wh.v, acc2);
        acc2 = MFMA32(gal, wh.v, acc2);
        acc2 = MFMA32(gah, wl.v, acc2);
    }

    const int jcol = wid * 32 + l31;
    float bj = bvec[jcol];
    float v[16];
#pragma unroll
    for (int r = 0; r < 16; ++r) {
        int e = (r & 3) + ((r >> 2) << 3) + (hf << 2);
        v[r] = acc2[r] + csh[e] * bj;
    }

    __syncthreads();   // B2: all waves done reading G before S overwrites union

#pragma unroll
    for (int r = 0; r < 16; ++r) {
        int e = (r & 3) + ((r >> 2) << 3) + (hf << 2);
        sm.S[e * SST + jcol] = v[r];
    }
    __syncthreads();   // B3

    // row sweeps: half-wave hw (0..15) handles rows 2hw, 2hw+1
    const int hw = tid >> 5;
    const int li = tid & 31;
    if (hw < 16) {
#pragma unroll
        for (int rr = 0; rr < 2; ++rr) {
            int row = 2 * hw + rr;
            float x[10];
            float m = -3.4e38f;
#pragma unroll
            for (int q = 0; q < 10; ++q) {
                x[q] = sm.S[row * SST + li + 32 * q];
                m = fmaxf(m, x[q]);
            }
#pragma unroll
            for (int off = 16; off; off >>= 1) m = fmaxf(m, __shfl_xor(m, off, 64));
            float ssum = 0.f;
#pragma unroll
            for (int q = 0; q < 10; ++q) ssum += __expf(x[q] - m);
#pragma unroll
            for (int off = 16; off; off >>= 1) ssum += __shfl_xor(ssum, off, 64);
            if (li == 0) { Mfin[row] = m; Ifin[row] = 1.0f / ssum; }
        }
    }
    __syncthreads();   // B4

    float wcol = 0.f;
#pragma unroll
    for (int r = 0; r < 16; ++r) {
        int e = (r & 3) + ((r >> 2) << 3) + (hf << 2);
        wcol += __expf(v[r] - Mfin[e]) * Ifin[e];
    }
    wcol += __shfl_xor(wcol, 32, 64);
    if (hf == 0) atomicAdd(&w[(size_t)i * N + jcol], wcol);
}

// ---------------- out[i][k] += sum_{j in chunk} w[i][j] * s[j][k] ----------------
// grid (320, 4): 4 j-chunks of 80 per row — 4x the blocks of the old version to
// hide load latency (old version ran at ~1.25 blocks/CU). out zeroed in prep.
__global__ __launch_bounds__(320) void out_gemm_kernel(
    const float* __restrict__ w, const float* __restrict__ s,
    float* __restrict__ out)
{
    const int i = blockIdx.x;
    const int jc = blockIdx.y;
    const int k = threadIdx.x;
    const float* wr = w + (size_t)i * N + jc * 80;
    const float* sp = s + (size_t)(jc * 80) * N + k;
    float a0 = 0.f, a1 = 0.f, a2 = 0.f, a3 = 0.f;
    for (int j = 0; j < 80; j += 4) {
        a0 += wr[j + 0] * sp[(size_t)(j + 0) * N];
        a1 += wr[j + 1] * sp[(size_t)(j + 1) * N];
        a2 += wr[j + 2] * sp[(size_t)(j + 2) * N];
        a3 += wr[j + 3] * sp[(size_t)(j + 3) * N];
    }
    atomicAdd(&out[(size_t)i * N + k], (a0 + a1) + (a2 + a3));
}

extern "C" void kernel_launch(void* const* d_in, const int* in_sizes, int n_in,
                              void* d_out, int out_size, void* d_ws, size_t ws_size,
                              hipStream_t stream)
{
    const float* s    = (const float*)d_in[0];
    const float* fut  = (const float*)d_in[1];
    const float* W    = (const float*)d_in[2];
    const float* bvec = (const float*)d_in[3];
    float* out = (float*)d_out;

    char* base = (char*)d_ws;
    float* wbuf  = (float*)base;                         // NN floats (409600 B)
    float* cpart = (float*)(base + 409600);              // 8*320 floats (10240 B)
    uint4* spH = (uint4*)(base + 419840);                // 204800 B
    uint4* spL = (uint4*)(base + 624640);                // 204800 B
    uint4* wpH = (uint4*)(base + 829440);                // 204800 B
    uint4* wpL = (uint4*)(base + 1034240);               // 204800 B

    prep_kernel<<<dim3(310), dim3(256), 0, stream>>>(
        s, W, wbuf, out, cpart, spH, spL, wpH, wpL);

    fused_kernel<<<dim3(3200), dim3(640), 0, stream>>>(
        fut, spH, spL, wpH, wpL, bvec, cpart, wbuf);

    out_gemm_kernel<<<dim3(320, 4), dim3(320), 0, stream>>>(wbuf, s, out);
}